// Round 1
// baseline (721.398 us; speedup 1.0000x reference)
//
#include <hip/hip_runtime.h>
#include <stdint.h>

#define NI_SMOOTH 0.1f
#define NI_ROUGH  0.05f
#define BETA      0.5f

// ---- Threefry-2x32 (20 rounds), bit-exact vs JAX's threefry2x32 primitive ----
__host__ __device__ __forceinline__ uint32_t tf_rotl(uint32_t x, int d) {
  return (x << d) | (x >> (32 - d));
}

__host__ __device__ __forceinline__ void threefry2x32(uint32_t k0, uint32_t k1,
                                                      uint32_t x0, uint32_t x1,
                                                      uint32_t* o0, uint32_t* o1) {
  uint32_t ks2 = k0 ^ k1 ^ 0x1BD11BDAu;
  x0 += k0; x1 += k1;
#define TF_R(r) { x0 += x1; x1 = tf_rotl(x1, (r)); x1 ^= x0; }
  TF_R(13) TF_R(15) TF_R(26) TF_R(6)
  x0 += k1;  x1 += ks2 + 1u;
  TF_R(17) TF_R(29) TF_R(16) TF_R(24)
  x0 += ks2; x1 += k0 + 2u;
  TF_R(13) TF_R(15) TF_R(26) TF_R(6)
  x0 += k0;  x1 += k1 + 3u;
  TF_R(17) TF_R(29) TF_R(16) TF_R(24)
  x0 += k1;  x1 += ks2 + 4u;
  TF_R(13) TF_R(15) TF_R(26) TF_R(6)
  x0 += ks2; x1 += k0 + 5u;
#undef TF_R
  *o0 = x0; *o1 = x1;
}

// partitionable random_bits: bits[i] = out0 ^ out1 of threefry(key, (0, i)).
// bernoulli(0.5): uniform < 0.5  <=>  MSB(bits) == 0  -> mask True ("rough").
__device__ __forceinline__ bool tf_rough(uint32_t k0, uint32_t k1, uint32_t c) {
  uint32_t o0, o1;
  threefry2x32(k0, k1, 0u, c, &o0, &o1);
  return ((o0 ^ o1) >> 31) == 0u;
}

__device__ __forceinline__ float upd(float m2, float m1, float c, float p1, float p2,
                                     float yv, bool rough) {
  float stencil = m2 - 4.0f * m1 + 6.0f * c - 4.0f * p1 + p2;
  float term = (1.0f - BETA) * stencil + BETA * (c - yv);
  return rough ? (c + NI_ROUGH * term) : (c - NI_SMOOTH * term);
}

__global__ __launch_bounds__(256) void rs_pass(const float* __restrict__ src,
                                               const float* __restrict__ y,
                                               float* __restrict__ dst,
                                               uint32_t k0, uint32_t k1, int n) {
  int t = blockIdx.x * blockDim.x + threadIdx.x;
  int base = t * 4;
  if (base >= n) return;

  if (base >= 4 && base + 8 <= n) {
    // fast path: all 4 outputs are interior (base+3 <= n-5)
    const float4 v  = *(const float4*)(src + base);
    const float2 lo = *(const float2*)(src + base - 2);
    const float2 hi = *(const float2*)(src + base + 4);
    const float4 yv = *(const float4*)(y + base);
    float s0 = lo.x, s1 = lo.y, s2 = v.x, s3 = v.y, s4 = v.z, s5 = v.w;
    float s6 = hi.x, s7 = hi.y;
    uint32_t c = (uint32_t)(base - 2);
    float4 o;
    o.x = upd(s0, s1, s2, s3, s4, yv.x, tf_rough(k0, k1, c + 0u));
    o.y = upd(s1, s2, s3, s4, s5, yv.y, tf_rough(k0, k1, c + 1u));
    o.z = upd(s2, s3, s4, s5, s6, yv.z, tf_rough(k0, k1, c + 2u));
    o.w = upd(s3, s4, s5, s6, s7, yv.w, tf_rough(k0, k1, c + 3u));
    *(float4*)(dst + base) = o;
  } else {
    // slow path: first and last groups
    for (int j = 0; j < 4; ++j) {
      int i = base + j;
      if (i >= n) break;
      float o;
      if (i == 0) {
        o = src[0];
      } else if (i == 1) {
        float st = -2.0f * src[0] + 5.0f * src[1] - 4.0f * src[2] + src[3];
        o = src[1] + NI_SMOOTH * ((1.0f - BETA) * st + BETA * (src[1] - y[1]));
      } else if (i >= n - 2) {
        o = y[i];
      } else {
        o = upd(src[i - 2], src[i - 1], src[i], src[i + 1], src[i + 2], y[i],
                tf_rough(k0, k1, (uint32_t)(i - 2)));
      }
      dst[i] = o;
    }
  }
}

extern "C" void kernel_launch(void* const* d_in, const int* in_sizes, int n_in,
                              void* d_out, int out_size, void* d_ws, size_t ws_size,
                              hipStream_t stream) {
  const float* y = (const float*)d_in[0];
  float* out = (float*)d_out;
  float* ws  = (float*)d_ws;
  int n = in_sizes[0];

  int threads = 256;
  int blocks = (n / 4 + threads - 1) / threads;

  const float* src = y;
  for (int k = 0; k < 9; ++k) {  // NUM_ITERATION + 1 passes
    // per-pass key: fold_in(key(42), k) = threefry2x32((0,42), (0,k))  [host math]
    uint32_t kk0, kk1;
    threefry2x32(0u, 42u, 0u, (uint32_t)k, &kk0, &kk1);
    float* dst = ((k & 1) == 0) ? out : ws;  // k=8 (last) lands in d_out
    rs_pass<<<blocks, threads, 0, stream>>>(src, y, dst, kk0, kk1, n);
    src = dst;
  }
}